// Round 6
// baseline (6973.676 us; speedup 1.0000x reference)
//
#include <hip/hip_runtime.h>
#include <stdint.h>

// Problem constants
#define SEQL 512
#define BATCH 64
#define EMB 300
#define EMBP 320          // E padded to multiple of 32
#define HID 1024
#define NWG 64            // workgroups; each owns 16 hidden units
#define UNITS 16
#define NCH 42            // 32 V chunks + 10 U chunks (of K=32)

typedef __attribute__((ext_vector_type(8))) short short8;
typedef __attribute__((ext_vector_type(4))) float f32x4;
typedef __attribute__((ext_vector_type(2))) unsigned int uint2v;

union Frag { short8 v; ushort u[8]; uint uu[4]; };
struct AF { uint2v lo, hi; };

__device__ __forceinline__ ushort f2bf(float f){
  union { float f; uint u; } c; c.f = f;
  return (ushort)((c.u + 0x7fffu + ((c.u >> 16) & 1u)) >> 16);   // RNE
}

struct Params {
  const ushort* xbf;   // [SEQL][BATCH][EMBP] bf16 embeddings
  ushort* hbuf;        // [2][BATCH][HID] bf16 double-buffered h
  float*  hfinal;      // [BATCH][HID] f32 final h
  int*    flags;       // [NWG] monotonic step counters
  ushort* wpack;       // [NWG][NCH][4 gates][64 lanes][8] bf16 B-fragments
  const float* V[4];   // V_i,V_f,V_c,V_o  [HID][HID]
  const float* U[4];   // U_i,U_f,U_c,U_o  [EMB][HID]
  const float* bia[4]; // b_i,b_f,b_c,b_o  [HID]
  const float* Wd;     // [HID][3]
  const float* bd;     // [3]
  float* out;          // [BATCH][3]
};

// ---------------- prep: gather embeddings -> bf16, zero h0 and flags ----------------
__global__ void __launch_bounds__(256) prep(const int* __restrict__ text,
                                            const float* __restrict__ tab,
                                            ushort* __restrict__ xbf,
                                            ushort* __restrict__ hbuf,
                                            int* __restrict__ flags){
  const int tid = blockIdx.x * blockDim.x + threadIdx.x;
  const int nth = gridDim.x * blockDim.x;
  uint* hz = (uint*)hbuf;
  for (int i = tid; i < BATCH*HID/2; i += nth) hz[i] = 0u;
  if (tid < NWG) flags[tid] = 0;
  const int nch = SEQL*BATCH*(EMBP/8);
  for (int ch = tid; ch < nch; ch += nth){
    const int e8 = ch % (EMBP/8);
    const int sb = ch / (EMBP/8);               // sb = s*BATCH + b
    const int b  = sb & (BATCH-1);
    const int s  = sb >> 6;
    const int tok = text[b*SEQL + s];
    union { ushort u[8]; uint4 v; } o;
    #pragma unroll
    for (int j = 0; j < 8; j++){
      const int e = e8*8 + j;
      o.u[j] = f2bf(e < EMB ? tab[(size_t)tok*EMB + e] : 0.f);
    }
    *(uint4*)&xbf[(size_t)sb*EMBP + e8*8] = o.v;
  }
}

// ---------------- packw: V/U -> bf16 MFMA B-fragments in ws ----------------
// B-frag (16x16x32): lane holds B[k][n], n = lane&15, k = (j>>2)*16 + ((lane>>4)&3)*4 + (j&3)
__global__ void __launch_bounds__(256) packw(Params p){
  const int bid  = blockIdx.x;
  const int w    = bid / NCH;
  const int kc   = bid % NCH;
  const int tid  = threadIdx.x;
  const int nt   = tid >> 6;
  const int lane = tid & 63;
  const int l4   = (lane >> 4) & 3;
  const int colg = w*UNITS + (lane & 15);
  Frag fr;
  #pragma unroll
  for (int j = 0; j < 8; j++){
    const int koff = ((j >> 2) << 4) + l4*4 + (j & 3);
    float v = 0.f;
    if (kc < 32){
      v = p.V[nt][(size_t)(kc*32 + koff)*HID + colg];
    } else {
      const int krow = (kc-32)*32 + koff;
      if (krow < EMB) v = p.U[nt][(size_t)krow*HID + colg];
    }
    fr.u[j] = f2bf(v);
  }
  *(short8*)&p.wpack[(((size_t)(w*NCH + kc)*4 + nt)*64 + lane)*8] = fr.v;
}

// ---- h@V software pipeline macros: ALL loads in the counted region are asm ----
#define WISSUE(c) { \
    const ushort* wp_ = wpk + (size_t)(wave + 4*(c))*2048 + lane*8; \
    asm volatile("global_load_dwordx4 %0, %4, off\n\t" \
                 "global_load_dwordx4 %1, %4, off offset:1024\n\t" \
                 "global_load_dwordx4 %2, %4, off offset:2048\n\t" \
                 "global_load_dwordx4 %3, %4, off offset:3072" \
                 : "=v"(wfr[(c)&3][0]), "=v"(wfr[(c)&3][1]), \
                   "=v"(wfr[(c)&3][2]), "=v"(wfr[(c)&3][3]) \
                 : "v"(wp_) : "memory"); }

#define VISSUE(c) { \
    const ushort* bp_ = hcur + (wave + 4*(c))*32 + qk; \
    _Pragma("unroll") \
    for (int m_ = 0; m_ < 4; m_++){ \
      const ushort* rp_ = bp_ + (size_t)(m_*16 + mrow)*HID; \
      asm volatile("global_load_dwordx2 %0, %2, off sc0 sc1\n\t" \
                   "global_load_dwordx2 %1, %2, off offset:32 sc0 sc1" \
                   : "=v"(afr[(c)&3][m_].lo), "=v"(afr[(c)&3][m_].hi) \
                   : "v"(rp_) : "memory"); \
    } }

#define VWAIT(n) { asm volatile("s_waitcnt vmcnt(" #n ")" ::: "memory"); \
                   __builtin_amdgcn_sched_barrier(0); }

#define VMFMA(c) { \
    _Pragma("unroll") \
    for (int m_ = 0; m_ < 4; m_++){ \
      Frag a_; \
      a_.uu[0] = afr[(c)&3][m_].lo[0]; a_.uu[1] = afr[(c)&3][m_].lo[1]; \
      a_.uu[2] = afr[(c)&3][m_].hi[0]; a_.uu[3] = afr[(c)&3][m_].hi[1]; \
      _Pragma("unroll") \
      for (int nt_ = 0; nt_ < 4; nt_++) \
        acc[m_][nt_] = __builtin_amdgcn_mfma_f32_16x16x32_bf16(a_.v, wfr[(c)&3][nt_], acc[m_][nt_], 0, 0, 0); \
    } }

// ---------------- persistent LSTM scan (256 threads) ----------------
__global__ void __launch_bounds__(256, 1) lstm_scan(Params p){
  __shared__ float buffer[2][64][68];   // cross-wave partial sums [buf][col][batch(+pad)]
  __shared__ float cst[UNITS][BATCH];   // cell state (f32)
  __shared__ float bias_l[64];          // 4 gates x 16 units

  const int w    = blockIdx.x;
  const int tid  = threadIdx.x;
  const int wave = tid >> 6;
  const int lane = tid & 63;
  const int n0   = w * UNITS;
  const int mrow = lane & 15;           // A row / D col lane index
  const int qk   = ((lane >> 4) & 3) << 2;
  const int nU   = (wave < 2) ? 3 : 2;  // U chunks per wave (10 = 3+3+2+2)
  const ushort* __restrict__ wpk = p.wpack + (size_t)w*NCH*2048;

  // per-wave producer flag set: wave consumes chunks wave+4c (c=0..7),
  // chunk kc's 32 columns come from WGs 2kc and 2kc+1.
  const int pl   = lane & 15;
  const int* fp  = p.flags + 2*(wave + 4*(pl >> 1)) + (pl & 1);

  if (tid < 64) bias_l[tid] = p.bia[tid >> 4][n0 + (tid & 15)];
  for (int i = tid; i < UNITS*BATCH; i += 256) (&cst[0][0])[i] = 0.f;
  __syncthreads();

  for (int t = 0; t < SEQL; t++){
    const ushort* __restrict__ xt = p.xbf + (size_t)t * (BATCH*EMBP);

    f32x4 acc[4][4];
    #pragma unroll
    for (int m = 0; m < 4; m++)
      #pragma unroll
      for (int nt = 0; nt < 4; nt++)
        acc[m][nt] = (f32x4){0.f, 0.f, 0.f, 0.f};

    // ---- x@U (h-independent; plain cached loads; overlaps producer skew) ----
    #pragma unroll
    for (int j3 = 0; j3 < 3; j3++){
      if (j3 < nU){
        const int kb  = (wave + 4*j3)*32;        // x column offset
        const int kcg = 32 + wave + 4*j3;        // global chunk in wpack
        Frag af[4];
        #pragma unroll
        for (int m = 0; m < 4; m++){
          const ushort* rp = xt + (size_t)(m*16 + mrow)*EMBP + kb + qk;
          uint2 lo = *(const uint2*)rp;
          uint2 hi = *(const uint2*)(rp + 16);
          af[m].uu[0] = lo.x; af[m].uu[1] = lo.y;
          af[m].uu[2] = hi.x; af[m].uu[3] = hi.y;
        }
        short8 wu[4];
        #pragma unroll
        for (int nt = 0; nt < 4; nt++)
          wu[nt] = *(const short8*)&wpk[(size_t)kcg*2048 + nt*512 + lane*8];
        #pragma unroll
        for (int m = 0; m < 4; m++)
          #pragma unroll
          for (int nt = 0; nt < 4; nt++)
            acc[m][nt] = __builtin_amdgcn_mfma_f32_16x16x32_bf16(af[m].v, wu[nt], acc[m][nt], 0, 0, 0);
      }
    }

    // ---- per-wave wait for this wave's 16 producers, then pipelined h@V ----
    if (t > 0){
      for (;;){
        int v;
        asm volatile("global_load_dword %0, %1, off sc0 sc1\n\t"
                     "s_waitcnt vmcnt(0)"
                     : "=v"(v) : "v"(fp) : "memory");
        if (__all(v >= t)) break;
        __builtin_amdgcn_s_sleep(1);
      }
      __builtin_amdgcn_sched_barrier(0);

      const ushort* __restrict__ hcur = p.hbuf + (size_t)(t & 1) * (BATCH*HID);
      AF afr[4][4];
      short8 wfr[4][4];
      WISSUE(0) VISSUE(0) WISSUE(1) VISSUE(1)
      WISSUE(2) VISSUE(2) WISSUE(3) VISSUE(3)
      VWAIT(36) VMFMA(0) WISSUE(4) VISSUE(4)
      VWAIT(36) VMFMA(1) WISSUE(5) VISSUE(5)
      VWAIT(36) VMFMA(2) WISSUE(6) VISSUE(6)
      VWAIT(36) VMFMA(3) WISSUE(7) VISSUE(7)
      VWAIT(36) VMFMA(4)
      VWAIT(24) VMFMA(5)
      VWAIT(12) VMFMA(6)
      VWAIT(0)  VMFMA(7)
    }

    // ---- cross-wave reduction: buffer[0]=w0+w2, buffer[1]=w1+w3 ----
    const int fq = (lane >> 4) << 2;
    if (wave >= 2){
      #pragma unroll
      for (int m = 0; m < 4; m++)
        #pragma unroll
        for (int nt = 0; nt < 4; nt++)
          *(f32x4*)&buffer[wave-2][nt*16 + mrow][m*16 + fq] = acc[m][nt];
    }
    __syncthreads();
    if (wave < 2){
      #pragma unroll
      for (int m = 0; m < 4; m++)
        #pragma unroll
        for (int nt = 0; nt < 4; nt++){
          f32x4 o = *(f32x4*)&buffer[wave][nt*16 + mrow][m*16 + fq];
          o += acc[m][nt];
          *(f32x4*)&buffer[wave][nt*16 + mrow][m*16 + fq] = o;
        }
    }
    __syncthreads();

    // ---- elementwise LSTM update; publish h_{t+1} coherently ----
    const int eb = tid & 63;            // batch
    const int uq = tid >> 6;            // unit quad
    ushort* __restrict__ hnxt = p.hbuf + (size_t)((t+1) & 1) * (BATCH*HID);
    ushort hout[4]; float hfv[4];
    #pragma unroll
    for (int rr = 0; rr < 4; rr++){
      const int u = uq*4 + rr;
      float g0 = buffer[0][ 0+u][eb] + buffer[1][ 0+u][eb] + bias_l[ 0+u];
      float g1 = buffer[0][16+u][eb] + buffer[1][16+u][eb] + bias_l[16+u];
      float g2 = buffer[0][32+u][eb] + buffer[1][32+u][eb] + bias_l[32+u];
      float g3 = buffer[0][48+u][eb] + buffer[1][48+u][eb] + bias_l[48+u];
      float ig = 1.f/(1.f + __expf(-g0));
      float fg = 1.f/(1.f + __expf(-g1));
      float gg = 2.f/(1.f + __expf(-2.f*g2)) - 1.f;
      float og = 1.f/(1.f + __expf(-g3));
      float cv = fg * cst[u][eb] + ig * gg;
      cst[u][eb] = cv;
      float hv = og * (2.f/(1.f + __expf(-2.f*cv)) - 1.f);
      hout[rr] = f2bf(hv);
      hfv[rr] = hv;
    }
    {
      union { ushort u[4]; uint2v v; } pk;
      pk.u[0]=hout[0]; pk.u[1]=hout[1]; pk.u[2]=hout[2]; pk.u[3]=hout[3];
      ushort* sa = &hnxt[(size_t)eb*HID + n0 + uq*4];
      asm volatile("global_store_dwordx2 %0, %1, off sc0 sc1"
                   :: "v"(sa), "v"(pk.v) : "memory");
      if (t == SEQL-1){
        f32x4 fv; fv[0]=hfv[0]; fv[1]=hfv[1]; fv[2]=hfv[2]; fv[3]=hfv[3];
        float* fa = &p.hfinal[(size_t)eb*HID + n0 + uq*4];
        asm volatile("global_store_dwordx4 %0, %1, off sc0 sc1"
                     :: "v"(fa), "v"(fv) : "memory");
      }
    }
    asm volatile("s_waitcnt vmcnt(0)" ::: "memory");   // h stores visible at IC
    __syncthreads();
    if (tid == 0){
      int tv = t + 1;
      asm volatile("global_store_dword %0, %1, off sc0 sc1"
                   :: "v"(p.flags + w), "v"(tv) : "memory");
    }
  }

  // ---- dense head: out[w] = h_n[w] @ Wd + bd (one WG per batch row) ----
  if (wave == 0){
    const int* ffp = p.flags + lane;
    for (;;){
      int v;
      asm volatile("global_load_dword %0, %1, off sc0 sc1\n\t"
                   "s_waitcnt vmcnt(0)"
                   : "=v"(v) : "v"(ffp) : "memory");
      if (__all(v >= SEQL)) break;
      __builtin_amdgcn_s_sleep(1);
    }
  }
  __syncthreads();

  float s0 = 0.f, s1 = 0.f, s2 = 0.f;
  const float* hf = p.hfinal + (size_t)w * HID;
  for (int k = tid; k < HID; k += 256){
    float hv;
    const float* ap = hf + k;
    asm volatile("global_load_dword %0, %1, off sc0 sc1\n\t"
                 "s_waitcnt vmcnt(0)"
                 : "=v"(hv) : "v"(ap) : "memory");
    s0 = fmaf(hv, p.Wd[k*3+0], s0);
    s1 = fmaf(hv, p.Wd[k*3+1], s1);
    s2 = fmaf(hv, p.Wd[k*3+2], s2);
  }
  float* red = &buffer[0][0][0];
  red[tid*3+0] = s0; red[tid*3+1] = s1; red[tid*3+2] = s2;
  __syncthreads();
  for (int off = 128; off > 0; off >>= 1){
    if (tid < off){
      red[tid*3+0] += red[(tid+off)*3+0];
      red[tid*3+1] += red[(tid+off)*3+1];
      red[tid*3+2] += red[(tid+off)*3+2];
    }
    __syncthreads();
  }
  if (tid < 3) p.out[w*3 + tid] = red[tid] + p.bd[tid];
}

// ---------------- host ----------------
extern "C" void kernel_launch(void* const* d_in, const int* in_sizes, int n_in,
                              void* d_out, int out_size, void* d_ws, size_t ws_size,
                              hipStream_t stream){
  const int*   text = (const int*)d_in[0];
  const float* tab  = (const float*)d_in[1];

  Params p;
  char* ws = (char*)d_ws;
  size_t off = 0;
  p.xbf    = (const ushort*)(ws + off); off += (size_t)SEQL*BATCH*EMBP*2;   // 20.0 MiB
  p.hbuf   = (ushort*)(ws + off);       off += (size_t)2*BATCH*HID*2;       // 256 KiB
  p.hfinal = (float*)(ws + off);        off += (size_t)BATCH*HID*4;         // 256 KiB
  p.flags  = (int*)(ws + off);          off += 256;
  p.wpack  = (ushort*)(ws + off);       off += (size_t)NWG*NCH*4*64*8*2;    // 10.5 MiB

  for (int g = 0; g < 4; g++){
    p.U[g]   = (const float*)d_in[2+g];
    p.V[g]   = (const float*)d_in[6+g];
    p.bia[g] = (const float*)d_in[10+g];
  }
  p.Wd  = (const float*)d_in[14];
  p.bd  = (const float*)d_in[15];
  p.out = (float*)d_out;

  prep<<<1024, 256, 0, stream>>>(text, tab, (ushort*)p.xbf, p.hbuf, p.flags);
  packw<<<NWG*NCH, 256, 0, stream>>>(p);
  lstm_scan<<<NWG, 256, 0, stream>>>(p);
}

// Round 7
// 4073.972 us; speedup vs baseline: 1.7118x; 1.7118x over previous
//
#include <hip/hip_runtime.h>
#include <stdint.h>

// Problem constants
#define SEQL 512
#define BATCH 64
#define EMB 300
#define EMBP 320          // E padded to multiple of 32
#define HID 1024
#define NWG 64            // workgroups; each owns 16 hidden units
#define UNITS 16
#define NCH 42            // 32 V chunks + 10 U chunks (of K=32)

typedef __attribute__((ext_vector_type(8))) short short8;
typedef __attribute__((ext_vector_type(4))) float f32x4;
typedef __attribute__((ext_vector_type(2))) unsigned int uint2v;

union Frag { short8 v; ushort u[8]; uint uu[4]; };
struct AF { uint2v lo, hi; };

__device__ __forceinline__ ushort f2bf(float f){
  union { float f; uint u; } c; c.f = f;
  return (ushort)((c.u + 0x7fffu + ((c.u >> 16) & 1u)) >> 16);   // RNE
}

struct Params {
  const ushort* xbf;   // [SEQL][BATCH][EMBP] bf16 embeddings
  ushort* hbuf;        // [2][NWG][64 batch][16 units] bf16, block-contiguous per WG
  float*  hfinal;      // [BATCH][HID] f32 final h
  int*    flags;       // [NWG] monotonic step counters
  ushort* wpack;       // [NWG][NCH][4 gates][64 lanes][8] bf16 B-fragments
  const float* V[4];   // V_i,V_f,V_c,V_o  [HID][HID]
  const float* U[4];   // U_i,U_f,U_c,U_o  [EMB][HID]
  const float* bia[4]; // b_i,b_f,b_c,b_o  [HID]
  const float* Wd;     // [HID][3]
  const float* bd;     // [3]
  float* out;          // [BATCH][3]
};

// ---------------- prep: gather embeddings -> bf16, zero h0 and flags ----------------
__global__ void __launch_bounds__(256) prep(const int* __restrict__ text,
                                            const float* __restrict__ tab,
                                            ushort* __restrict__ xbf,
                                            ushort* __restrict__ hbuf,
                                            int* __restrict__ flags){
  const int tid = blockIdx.x * blockDim.x + threadIdx.x;
  const int nth = gridDim.x * blockDim.x;
  uint* hz = (uint*)hbuf;                       // zero hbuf[0]: NWG*64*16 bf16 = 32768 dwords
  for (int i = tid; i < NWG*64*16/2; i += nth) hz[i] = 0u;
  if (tid < NWG) flags[tid] = 0;
  const int nch = SEQL*BATCH*(EMBP/8);
  for (int ch = tid; ch < nch; ch += nth){
    const int e8 = ch % (EMBP/8);
    const int sb = ch / (EMBP/8);               // sb = s*BATCH + b
    const int b  = sb & (BATCH-1);
    const int s  = sb >> 6;
    const int tok = text[b*SEQL + s];
    union { ushort u[8]; uint4 v; } o;
    #pragma unroll
    for (int j = 0; j < 8; j++){
      const int e = e8*8 + j;
      o.u[j] = f2bf(e < EMB ? tab[(size_t)tok*EMB + e] : 0.f);
    }
    *(uint4*)&xbf[(size_t)sb*EMBP + e8*8] = o.v;
  }
}

// ---------------- packw: V/U -> bf16 MFMA B-fragments in ws ----------------
// B-frag (16x16x32): lane holds B[k][n], n = lane&15, k = (j>>2)*16 + ((lane>>4)&3)*4 + (j&3)
__global__ void __launch_bounds__(256) packw(Params p){
  const int bid  = blockIdx.x;
  const int w    = bid / NCH;
  const int kc   = bid % NCH;
  const int tid  = threadIdx.x;
  const int nt   = tid >> 6;
  const int lane = tid & 63;
  const int l4   = (lane >> 4) & 3;
  const int colg = w*UNITS + (lane & 15);
  Frag fr;
  #pragma unroll
  for (int j = 0; j < 8; j++){
    const int koff = ((j >> 2) << 4) + l4*4 + (j & 3);
    float v = 0.f;
    if (kc < 32){
      v = p.V[nt][(size_t)(kc*32 + koff)*HID + colg];
    } else {
      const int krow = (kc-32)*32 + koff;
      if (krow < EMB) v = p.U[nt][(size_t)krow*HID + colg];
    }
    fr.u[j] = f2bf(v);
  }
  *(short8*)&p.wpack[(((size_t)(w*NCH + kc)*4 + nt)*64 + lane)*8] = fr.v;
}

// ---- h@V software pipeline macros: ALL loads in the counted region are asm ----
#define WISSUE(c) { \
    const ushort* wp_ = wpk + (size_t)(wave + 4*(c))*2048 + lane*8; \
    asm volatile("global_load_dwordx4 %0, %4, off\n\t" \
                 "global_load_dwordx4 %1, %4, off offset:1024\n\t" \
                 "global_load_dwordx4 %2, %4, off offset:2048\n\t" \
                 "global_load_dwordx4 %3, %4, off offset:3072" \
                 : "=v"(wfr[(c)&3][0]), "=v"(wfr[(c)&3][1]), \
                   "=v"(wfr[(c)&3][2]), "=v"(wfr[(c)&3][3]) \
                 : "v"(wp_) : "memory"); }

// chunk kc = wave+4c covers units 32kc..32kc+31 = blocks 2kc (lo 16) and 2kc+1 (hi 16).
// lane (mrow,qk) m-tile m: lo = blk[2kc][m*16+mrow][qk..qk+3], hi = same +2048B (next blk)
#define VISSUE(c) { \
    const ushort* bp_ = hcur + (size_t)(wave + 4*(c))*2048 + qk; \
    _Pragma("unroll") \
    for (int m_ = 0; m_ < 4; m_++){ \
      const ushort* rp_ = bp_ + (m_*16 + mrow)*16; \
      asm volatile("global_load_dwordx2 %0, %2, off sc0 sc1\n\t" \
                   "global_load_dwordx2 %1, %2, off offset:2048 sc0 sc1" \
                   : "=v"(afr[(c)&3][m_].lo), "=v"(afr[(c)&3][m_].hi) \
                   : "v"(rp_) : "memory"); \
    } }

#define VWAIT(n) { asm volatile("s_waitcnt vmcnt(" #n ")" ::: "memory"); \
                   __builtin_amdgcn_sched_barrier(0); }

#define VMFMA(c) { \
    _Pragma("unroll") \
    for (int m_ = 0; m_ < 4; m_++){ \
      Frag a_; \
      a_.uu[0] = afr[(c)&3][m_].lo[0]; a_.uu[1] = afr[(c)&3][m_].lo[1]; \
      a_.uu[2] = afr[(c)&3][m_].hi[0]; a_.uu[3] = afr[(c)&3][m_].hi[1]; \
      _Pragma("unroll") \
      for (int nt_ = 0; nt_ < 4; nt_++) \
        acc[m_][nt_] = __builtin_amdgcn_mfma_f32_16x16x32_bf16(a_.v, wfr[(c)&3][nt_], acc[m_][nt_], 0, 0, 0); \
    } }

// ---------------- persistent LSTM scan (256 threads) ----------------
__global__ void __launch_bounds__(256, 1) lstm_scan(Params p){
  __shared__ float buffer[2][64][68];   // cross-wave partial sums [buf][col][batch(+pad)]
  __shared__ float cst[UNITS][BATCH];   // cell state (f32)
  __shared__ float bias_l[64];          // 4 gates x 16 units

  const int w    = blockIdx.x;
  const int tid  = threadIdx.x;
  const int wave = tid >> 6;
  const int lane = tid & 63;
  const int n0   = w * UNITS;
  const int mrow = lane & 15;           // A row / D col lane index
  const int qk   = ((lane >> 4) & 3) << 2;
  const int nU   = (wave < 2) ? 3 : 2;  // U chunks per wave (10 = 3+3+2+2)
  const ushort* __restrict__ wpk = p.wpack + (size_t)w*NCH*2048;

  // per-wave producer flag set: wave consumes chunks wave+4c (c=0..7),
  // chunk kc's 32 units come from WGs 2kc and 2kc+1.
  const int pl   = lane & 15;
  const int* fp  = p.flags + 2*(wave + 4*(pl >> 1)) + (pl & 1);

  if (tid < 64) bias_l[tid] = p.bia[tid >> 4][n0 + (tid & 15)];
  for (int i = tid; i < UNITS*BATCH; i += 256) (&cst[0][0])[i] = 0.f;
  __syncthreads();

  for (int t = 0; t < SEQL; t++){
    const ushort* __restrict__ xt = p.xbf + (size_t)t * (BATCH*EMBP);

    f32x4 acc[4][4];
    #pragma unroll
    for (int m = 0; m < 4; m++)
      #pragma unroll
      for (int nt = 0; nt < 4; nt++)
        acc[m][nt] = (f32x4){0.f, 0.f, 0.f, 0.f};

    // ---- x@U (h-independent; plain cached loads; overlaps producer skew) ----
    #pragma unroll
    for (int j3 = 0; j3 < 3; j3++){
      if (j3 < nU){
        const int kb  = (wave + 4*j3)*32;        // x column offset
        const int kcg = 32 + wave + 4*j3;        // global chunk in wpack
        Frag af[4];
        #pragma unroll
        for (int m = 0; m < 4; m++){
          const ushort* rp = xt + (size_t)(m*16 + mrow)*EMBP + kb + qk;
          uint2 lo = *(const uint2*)rp;
          uint2 hi = *(const uint2*)(rp + 16);
          af[m].uu[0] = lo.x; af[m].uu[1] = lo.y;
          af[m].uu[2] = hi.x; af[m].uu[3] = hi.y;
        }
        short8 wu[4];
        #pragma unroll
        for (int nt = 0; nt < 4; nt++)
          wu[nt] = *(const short8*)&wpk[(size_t)kcg*2048 + nt*512 + lane*8];
        #pragma unroll
        for (int m = 0; m < 4; m++)
          #pragma unroll
          for (int nt = 0; nt < 4; nt++)
            acc[m][nt] = __builtin_amdgcn_mfma_f32_16x16x32_bf16(af[m].v, wu[nt], acc[m][nt], 0, 0, 0);
      }
    }

    // ---- per-wave wait for this wave's 16 producers, then pipelined h@V ----
    if (t > 0){
      for (;;){
        int v;
        asm volatile("global_load_dword %0, %1, off sc0 sc1\n\t"
                     "s_waitcnt vmcnt(0)"
                     : "=v"(v) : "v"(fp) : "memory");
        if (__all(v >= t)) break;
        __builtin_amdgcn_s_sleep(1);
      }
      __builtin_amdgcn_sched_barrier(0);

      const ushort* __restrict__ hcur = p.hbuf + (size_t)(t & 1) * (NWG*64*16);
      AF afr[4][4];
      short8 wfr[4][4];
      WISSUE(0) VISSUE(0) WISSUE(1) VISSUE(1)
      WISSUE(2) VISSUE(2) WISSUE(3) VISSUE(3)
      VWAIT(36) VMFMA(0) WISSUE(4) VISSUE(4)
      VWAIT(36) VMFMA(1) WISSUE(5) VISSUE(5)
      VWAIT(36) VMFMA(2) WISSUE(6) VISSUE(6)
      VWAIT(36) VMFMA(3) WISSUE(7) VISSUE(7)
      VWAIT(36) VMFMA(4)
      VWAIT(24) VMFMA(5)
      VWAIT(12) VMFMA(6)
      VWAIT(0)  VMFMA(7)
    }

    // ---- cross-wave reduction: buffer[0]=w0+w2, buffer[1]=w1+w3 ----
    const int fq = (lane >> 4) << 2;
    if (wave >= 2){
      #pragma unroll
      for (int m = 0; m < 4; m++)
        #pragma unroll
        for (int nt = 0; nt < 4; nt++)
          *(f32x4*)&buffer[wave-2][nt*16 + mrow][m*16 + fq] = acc[m][nt];
    }
    __syncthreads();
    if (wave < 2){
      #pragma unroll
      for (int m = 0; m < 4; m++)
        #pragma unroll
        for (int nt = 0; nt < 4; nt++){
          f32x4 o = *(f32x4*)&buffer[wave][nt*16 + mrow][m*16 + fq];
          o += acc[m][nt];
          *(f32x4*)&buffer[wave][nt*16 + mrow][m*16 + fq] = o;
        }
    }
    __syncthreads();

    // ---- elementwise LSTM update; publish h_{t+1} as one contiguous 2KB block ----
    const int eb = tid & 63;            // batch
    const int uq = tid >> 6;            // unit quad
    ushort* __restrict__ hnxt = p.hbuf + (size_t)((t+1) & 1) * (NWG*64*16);
    ushort hout[4]; float hfv[4];
    #pragma unroll
    for (int rr = 0; rr < 4; rr++){
      const int u = uq*4 + rr;
      float g0 = buffer[0][ 0+u][eb] + buffer[1][ 0+u][eb] + bias_l[ 0+u];
      float g1 = buffer[0][16+u][eb] + buffer[1][16+u][eb] + bias_l[16+u];
      float g2 = buffer[0][32+u][eb] + buffer[1][32+u][eb] + bias_l[32+u];
      float g3 = buffer[0][48+u][eb] + buffer[1][48+u][eb] + bias_l[48+u];
      float ig = 1.f/(1.f + __expf(-g0));
      float fg = 1.f/(1.f + __expf(-g1));
      float gg = 2.f/(1.f + __expf(-2.f*g2)) - 1.f;
      float og = 1.f/(1.f + __expf(-g3));
      float cv = fg * cst[u][eb] + ig * gg;
      cst[u][eb] = cv;
      float hv = og * (2.f/(1.f + __expf(-2.f*cv)) - 1.f);
      hout[rr] = f2bf(hv);
      hfv[rr] = hv;
    }
    {
      union { ushort u[4]; uint2v v; } pk;
      pk.u[0]=hout[0]; pk.u[1]=hout[1]; pk.u[2]=hout[2]; pk.u[3]=hout[3];
      ushort* sa = &hnxt[(size_t)w*1024 + eb*16 + uq*4];   // blk[w][eb][uq*4]
      asm volatile("global_store_dwordx2 %0, %1, off sc0 sc1"
                   :: "v"(sa), "v"(pk.v) : "memory");
      if (t == SEQL-1){
        f32x4 fv; fv[0]=hfv[0]; fv[1]=hfv[1]; fv[2]=hfv[2]; fv[3]=hfv[3];
        float* fa = &p.hfinal[(size_t)eb*HID + n0 + uq*4];
        asm volatile("global_store_dwordx4 %0, %1, off sc0 sc1"
                     :: "v"(fa), "v"(fv) : "memory");
      }
    }
    asm volatile("s_waitcnt vmcnt(0)" ::: "memory");   // h block visible at IC
    __syncthreads();
    if (tid == 0){
      int tv = t + 1;
      asm volatile("global_store_dword %0, %1, off sc0 sc1"
                   :: "v"(p.flags + w), "v"(tv) : "memory");
    }
  }

  // ---- dense head: out[w] = h_n[w] @ Wd + bd (one WG per batch row) ----
  if (wave == 0){
    const int* ffp = p.flags + lane;
    for (;;){
      int v;
      asm volatile("global_load_dword %0, %1, off sc0 sc1\n\t"
                   "s_waitcnt vmcnt(0)"
                   : "=v"(v) : "v"(ffp) : "memory");
      if (__all(v >= SEQL)) break;
      __builtin_amdgcn_s_sleep(1);
    }
  }
  __syncthreads();

  float s0 = 0.f, s1 = 0.f, s2 = 0.f;
  const float* hf = p.hfinal + (size_t)w * HID;
  for (int k = tid; k < HID; k += 256){
    float hv;
    const float* ap = hf + k;
    asm volatile("global_load_dword %0, %1, off sc0 sc1\n\t"
                 "s_waitcnt vmcnt(0)"
                 : "=v"(hv) : "v"(ap) : "memory");
    s0 = fmaf(hv, p.Wd[k*3+0], s0);
    s1 = fmaf(hv, p.Wd[k*3+1], s1);
    s2 = fmaf(hv, p.Wd[k*3+2], s2);
  }
  float* red = &buffer[0][0][0];
  red[tid*3+0] = s0; red[tid*3+1] = s1; red[tid*3+2] = s2;
  __syncthreads();
  for (int off = 128; off > 0; off >>= 1){
    if (tid < off){
      red[tid*3+0] += red[(tid+off)*3+0];
      red[tid*3+1] += red[(tid+off)*3+1];
      red[tid*3+2] += red[(tid+off)*3+2];
    }
    __syncthreads();
  }
  if (tid < 3) p.out[w*3 + tid] = red[tid] + p.bd[tid];
}

// ---------------- host ----------------
extern "C" void kernel_launch(void* const* d_in, const int* in_sizes, int n_in,
                              void* d_out, int out_size, void* d_ws, size_t ws_size,
                              hipStream_t stream){
  const int*   text = (const int*)d_in[0];
  const float* tab  = (const float*)d_in[1];

  Params p;
  char* ws = (char*)d_ws;
  size_t off = 0;
  p.xbf    = (const ushort*)(ws + off); off += (size_t)SEQL*BATCH*EMBP*2;   // 20.0 MiB
  p.hbuf   = (ushort*)(ws + off);       off += (size_t)2*NWG*64*16*2;       // 256 KiB
  p.hfinal = (float*)(ws + off);        off += (size_t)BATCH*HID*4;         // 256 KiB
  p.flags  = (int*)(ws + off);          off += 256;
  p.wpack  = (ushort*)(ws + off);       off += (size_t)NWG*NCH*4*64*8*2;    // 10.5 MiB

  for (int g = 0; g < 4; g++){
    p.U[g]   = (const float*)d_in[2+g];
    p.V[g]   = (const float*)d_in[6+g];
    p.bia[g] = (const float*)d_in[10+g];
  }
  p.Wd  = (const float*)d_in[14];
  p.bd  = (const float*)d_in[15];
  p.out = (float*)d_out;

  prep<<<1024, 256, 0, stream>>>(text, tab, (ushort*)p.xbf, (ushort*)p.hbuf, p.flags);
  packw<<<NWG*NCH, 256, 0, stream>>>(p);
  lstm_scan<<<NWG, 256, 0, stream>>>(p);
}